// Round 8
// baseline (388.912 us; speedup 1.0000x reference)
//
#include <hip/hip_runtime.h>
#include <math.h>

// Problem constants
#define NSEQ 4
#define BATCH 256
#define T 64
#define FIN 32
#define S 512
#define KTOT 544     // FIN + S unified k-dimension

// Pipelined decomposition: 4 lanes concurrent (lane i lags i-1 by 1 step).
// Per lane: 16 groups x 16 rows, 4 slice-WGs x 128 cols. 4*16*4 = 256 WGs.
// NT=512 (8 waves). Wave -> one 16x16 col-tile, 17 K-tiles of
// mfma_f32_16x16x32_bf16, SPLIT-BF16 (hi+lo residual, 3 products).
//
// R8: attack the TRAFFIC SHAPE (R5/R6/R7 all hit the same ~320us floor on
// different handshake encodings -> handshake is not the residual):
//  * COALESCED ring stores: epilogue writes tanh results to h_lds (8KB),
//    barrier, then ONE contiguous dwordx4 per thread (512 aligned 16B
//    stores/WG/step) instead of 2048 scattered single-dword stores at
//    512B stride. 4x fewer MALL store requests, line-aligned.
//  * OWN-BLOCK BYPASS: own 128 cols of h_{t-1} come from h_lds; ring h
//    load shrinks to the 3 sibling blocks (-25% h read traffic).
//  * CHEAP POLL -> SINGLE LOAD: poll canary/stamp lines only (4x16B,
//    broadcast-coalesced), then load data once after accept. Sound
//    ordering (R7 loaded data with the canary in one clause -> could see
//    new canary + stale data; MALL order within a clause is unordered).
//  * dual MFMA accumulator chains (kt<9 / kt>=9) halve the 51-deep
//    dependent chain.
// Protocol (canary + loose guards + poison-keyed FLAG_MAGIC init, all
// sc0 sc1 / MALL) carried from R7 unchanged.
#define NT 512
#define NWG 256
#define RPG 16
#define SW 128       // cols per slice-WG
#define DEPTH 4
#define NKT 17       // K-tiles of 32 (544/32)

// ws float offsets (content is POISON at launch - never read before init)
#define RING_SZ  (4ull * DEPTH * BATCH * S)        // 8 MB state ring
#define OUTP_OFF RING_SZ                            // [gid][sl][16] partials
#define CTL_OFF  (RING_SZ + 16384ull)               // ctl + canary area

#define FLAG_MAGIC 0x13572468u

#define AS 552   // A-LDS row stride in bf16 elems (544 + 8 pad)

typedef __attribute__((ext_vector_type(8))) short short8;      // 8 bf16
typedef __attribute__((ext_vector_type(4))) float f32x4;       // MFMA C/D
typedef __attribute__((ext_vector_type(4))) unsigned u32x4;    // asm 4-dword

// ---- split-bf16: value = hi (truncated bf16) + lo (bf16 of residual) ------
__device__ __forceinline__ unsigned short bf_hi(float f) {
  return (unsigned short)(__float_as_uint(f) >> 16);
}
__device__ __forceinline__ float bf_hi_f(float f) {
  return __uint_as_float(__float_as_uint(f) & 0xFFFF0000u);
}
__device__ __forceinline__ unsigned umin4(u32x4 v) {
  unsigned a = v[0] < v[1] ? v[0] : v[1];
  unsigned b = v[2] < v[3] ? v[2] : v[3];
  return a < b ? a : b;
}
__device__ __forceinline__ bool alleq4(u32x4 v, unsigned m) {
  return v[0] == m && v[1] == m && v[2] == m && v[3] == m;
}

// ---- MALL (system scope) coherent I/O: sc0 sc1 everywhere -----------------
__device__ __forceinline__ void cstoreu_glb(unsigned* p, unsigned v) {
  asm volatile("global_store_dword %0, %1, off sc0 sc1" :: "v"(p), "v"(v) : "memory");
}
__device__ __forceinline__ void cstore4_glb(unsigned* p, u32x4 v) {
  asm volatile("global_store_dwordx4 %0, %1, off sc0 sc1" :: "v"(p), "v"(v) : "memory");
}
__device__ __forceinline__ void cstore4f_glb(float* p, f32x4 v) {
  asm volatile("global_store_dwordx4 %0, %1, off sc0 sc1" :: "v"(p), "v"(v) : "memory");
}
__device__ __forceinline__ u32x4 cld4_glb(const unsigned* p) {
  u32x4 v;
  asm volatile("global_load_dwordx4 %0, %1, off sc0 sc1\n\ts_waitcnt vmcnt(0)"
               : "=v"(v) : "v"(p) : "memory");
  return v;
}
__device__ __forceinline__ void cstore1(float* p, float v) {
  asm volatile("global_store_dword %0, %1, off sc0 sc1" :: "v"(p), "v"(v) : "memory");
}
__device__ __forceinline__ float cload1(const float* p) {
  float v;
  asm volatile("global_load_dword %0, %1, off sc0 sc1\n\ts_waitcnt vmcnt(0)"
               : "=v"(v) : "v"(p) : "memory");
  return v;
}
// cheap poll: 4 x 16B control lines, one vmcnt
__device__ __forceinline__ void poll4(u32x4* a, u32x4* b, u32x4* c, u32x4* d,
                                      const unsigned* pa, const unsigned* pb,
                                      const unsigned* pc, const unsigned* pd) {
  asm volatile(
      "global_load_dwordx4 %0, %4, off sc0 sc1\n\t"
      "global_load_dwordx4 %1, %5, off sc0 sc1\n\t"
      "global_load_dwordx4 %2, %6, off sc0 sc1\n\t"
      "global_load_dwordx4 %3, %7, off sc0 sc1\n\t"
      "s_waitcnt vmcnt(0)"
      : "=&v"(*a), "=&v"(*b), "=&v"(*c), "=&v"(*d)
      : "v"(pa), "v"(pb), "v"(pc), "v"(pd) : "memory");
}
// 3 sibling h blocks + 4 p blocks, one vmcnt
__device__ __forceinline__ void ld_h3p4(float4* h3, float4* p,
                                        const float* ph0, const float* ph1,
                                        const float* ph2, const float* pp) {
  asm volatile(
      "global_load_dwordx4 %0, %7, off sc0 sc1\n\t"
      "global_load_dwordx4 %1, %8, off sc0 sc1\n\t"
      "global_load_dwordx4 %2, %9, off sc0 sc1\n\t"
      "global_load_dwordx4 %3, %10, off sc0 sc1\n\t"
      "global_load_dwordx4 %4, %10, off offset:512 sc0 sc1\n\t"
      "global_load_dwordx4 %5, %10, off offset:1024 sc0 sc1\n\t"
      "global_load_dwordx4 %6, %10, off offset:1536 sc0 sc1\n\t"
      "s_waitcnt vmcnt(0)"
      : "=&v"(h3[0]), "=&v"(h3[1]), "=&v"(h3[2]),
        "=&v"(p[0]), "=&v"(p[1]), "=&v"(p[2]), "=&v"(p[3])
      : "v"(ph0), "v"(ph1), "v"(ph2), "v"(pp) : "memory");
}
__device__ __forceinline__ void ld_h3(float4* h3, const float* ph0,
                                      const float* ph1, const float* ph2) {
  asm volatile(
      "global_load_dwordx4 %0, %3, off sc0 sc1\n\t"
      "global_load_dwordx4 %1, %4, off sc0 sc1\n\t"
      "global_load_dwordx4 %2, %5, off sc0 sc1\n\t"
      "s_waitcnt vmcnt(0)"
      : "=&v"(h3[0]), "=&v"(h3[1]), "=&v"(h3[2])
      : "v"(ph0), "v"(ph1), "v"(ph2) : "memory");
}
__device__ __forceinline__ void cload_row(float4* d, const float* p) {
  asm volatile(
      "global_load_dwordx4 %0, %4, off sc0 sc1\n\t"
      "global_load_dwordx4 %1, %4, off offset:512 sc0 sc1\n\t"
      "global_load_dwordx4 %2, %4, off offset:1024 sc0 sc1\n\t"
      "global_load_dwordx4 %3, %4, off offset:1536 sc0 sc1\n\t"
      "s_waitcnt vmcnt(0)"
      : "=&v"(d[0]), "=&v"(d[1]), "=&v"(d[2]), "=&v"(d[3])
      : "v"(p) : "memory");
}

// ctl layout (dwords, stride 64 per gid; stamps and flags on different
// 128B lines):
//   ctl + gid*64 + [0..3]      : per-slice step stamps (one 128B line)
//   ctl + gid*64 + 32 + [0..3] : per-slice init flags (next 128B line)
//   ctl + 8192                  : canary[lane][slot][grp][row][slice]

extern "C" __global__ void __launch_bounds__(NT, 1)
rnn_mfma(const float* __restrict__ x,      // [4][256][64][32]
         const float* __restrict__ Wcell,  // [4][544][512]
         const float* __restrict__ bcell,  // [4][512]
         const float* __restrict__ Wcomb,  // [3][1024]
         const float* __restrict__ bcomb,  // [3]
         const float* __restrict__ Wout,   // [512]
         float* __restrict__ out,          // [1024] = [lane][batch]
         float* __restrict__ ws)
{
  // XCD-grouped block mapping (perf heuristic only; correctness is
  // placement-independent: everything goes through MALL).
  const int b    = blockIdx.x;
  const int o    = b >> 3;
  const int grp  = (b & 7) + 8 * (o >> 4);
  const int sub  = o & 15;
  const int lane = sub >> 2;
  const int sl   = sub & 3;
  const int gid  = lane * 16 + grp;
  const int r0 = grp * RPG, sb = sl * SW;
  const int tid = threadIdx.x;

  __shared__ __align__(16) unsigned short A1[RPG * AS];  // 17.3 KB hi [x|hc]
  __shared__ __align__(16) unsigned short A2[RPG * AS];  // 17.3 KB lo
  __shared__ __align__(16) float h_lds[RPG * SW];        //  8.0 KB own h block
  __shared__ float wg_lds[2 * S];                        //  4.0 KB gate weights
  __shared__ float obuf[128];
  __shared__ float fbuf[64];

  float* ring = ws;
  unsigned* ctl     = (unsigned*)(ws + CTL_OFF);
  unsigned* st_own  = ctl + gid * 64;
  unsigned* st_cons = ctl + (gid + 16) * 64;   // valid iff lane<3
  unsigned* st_mine = st_own + sl;
  unsigned* flg_own  = st_own + 32;
  unsigned* flg_prod = ctl + (gid - 16) * 64 + 32;  // valid iff lane>0
  unsigned* flg_cons = st_cons + 32;
  unsigned* can = ctl + 8192;                  // canary array base
  const unsigned* psc = (lane < 3) ? st_cons : st_own;

  // ---- init: zero own canary slice + (sl0) stamp line, flag, wait set ----
  if (tid < 64) {
    const int slot = tid >> 4, row = tid & 15;
    cstoreu_glb(can + ((((lane * 4 + slot) * 16 + grp) * 16 + row) * 4 + sl), 0u);
  }
  if (sl == 0 && tid == 0) {
    const u32x4 z = {0u, 0u, 0u, 0u};
    cstore4_glb(st_own, z);
  }
  asm volatile("s_waitcnt vmcnt(0)" ::: "memory");
  __syncthreads();                 // all zero-stores of this WG drained
  if (tid == 0) {
    cstoreu_glb(flg_own + sl, FLAG_MAGIC);
    for (;;) {
      bool ok = alleq4(cld4_glb(flg_own), FLAG_MAGIC);
      if (lane > 0) ok &= alleq4(cld4_glb(flg_prod), FLAG_MAGIC);
      if (lane < 3) ok &= alleq4(cld4_glb(flg_cons), FLAG_MAGIC);
      if (ok) break;
      __builtin_amdgcn_s_sleep(2);
    }
  }

  // ---- per-thread constants ----
  const float* Wc = Wcell + (size_t)lane * KTOT * S;
  // MFMA mapping: wave wt (0..7) owns cols [sb+wt*16, +16); within wave:
  //   A-frag: row m = wl&15, k = q*8+j   (q = wl>>4)
  //   B-frag: col n = wl&15, k = q*8+j
  //   C/D:    col  = wl&15, row = q*4+reg
  const int wl = tid & 63, wt = tid >> 6;
  const int bn = wl & 15, q = wl >> 4;
  const int ncol = sb + wt * 16 + bn;
  short8 B1[NKT], B2[NKT];   // split-bf16 weight frags: 136 regs, static
  #pragma unroll
  for (int kt = 0; kt < NKT; ++kt) {
    short8 b1, b2;
    #pragma unroll
    for (int j = 0; j < 8; ++j) {
      const float w = Wc[(size_t)(kt * 32 + q * 8 + j) * S + ncol];
      b1[j] = (short)bf_hi(w);
      b2[j] = (short)bf_hi(w - bf_hi_f(w));
    }
    B1[kt] = b1; B2[kt] = b2;
  }
  const float bcv = bcell[lane * S + ncol];
  const float wov = Wout[ncol];
  for (int idx = tid; idx < 2 * S; idx += NT)
    wg_lds[idx] = (lane > 0) ? Wcomb[(size_t)(lane - 1) * 2 * S + idx] : 0.0f;
  const float bg = (lane > 0) ? bcomb[lane - 1] : 0.0f;
  // stage/gate mapping: 32 threads per row, 16 rows; wave w owns rows 2w,2w+1
  const int grow = tid >> 5, gch = tid & 31;
  __syncthreads();   // gates on tid0's flag wait too

  float oacc[4] = {0.f, 0.f, 0.f, 0.f};

  for (int t = 0; t < T; ++t) {
    // ---- phase A: x stage (per-wave rows); x load overlaps the poll ------
    {
      const float f0 = x[(((size_t)lane * BATCH + r0 + grow) * T + t) * FIN + gch];
      A1[grow * AS + gch] = bf_hi(f0);
      A2[grow * AS + gch] = bf_hi(f0 - bf_hi_f(f0));
    }

    // ---- phase B: cheap canary poll, then ONE data load ------------------
    {
      const unsigned* hce = (t > 0)
          ? can + (((lane * 4 + ((t - 1) & 3)) * 16 + grp) * 16 + grow) * 4
          : st_own;
      const unsigned* pce = (lane > 0)
          ? can + ((((lane - 1) * 4 + (t & 3)) * 16 + grp) * 16 + grow) * 4
          : st_own;
      for (;;) {
        u32x4 hc, pc, so, sc;
        poll4(&hc, &pc, &so, &sc, hce, pce, st_own, psc);
        bool ok = ((int)umin4(so) >= t - 2);          // sibling slot reuse
        if (lane < 3) ok &= ((int)umin4(sc) >= t - 3); // consumer slot reuse
        if (t > 0)    ok &= alleq4(hc, (unsigned)t);
        if (lane > 0) ok &= alleq4(pc, (unsigned)(t + 1));
        if (ok) break;
        __builtin_amdgcn_s_sleep(1);
      }

      float4 hv[4], pv[4];
      const float* hrow = ring + ((size_t)(lane * DEPTH + ((t - 1) & 3)) * BATCH + r0 + grow) * S + gch * 4;
      const float* prow = ring + ((size_t)((lane - 1) * DEPTH + (t & 3)) * BATCH + r0 + grow) * S + gch * 4;
      if (t > 0) {
        const float4 ownv = *(const float4*)&h_lds[grow * SW + gch * 4];
        float4 h3[3];
        // wave-uniform switch keeps every hv index literal (no scratch)
        switch (sl) {
          case 0:
            if (lane > 0) ld_h3p4(h3, pv, hrow + 1*SW, hrow + 2*SW, hrow + 3*SW, prow);
            else          ld_h3(h3, hrow + 1*SW, hrow + 2*SW, hrow + 3*SW);
            hv[1] = h3[0]; hv[2] = h3[1]; hv[3] = h3[2]; hv[0] = ownv; break;
          case 1:
            if (lane > 0) ld_h3p4(h3, pv, hrow + 0*SW, hrow + 2*SW, hrow + 3*SW, prow);
            else          ld_h3(h3, hrow + 0*SW, hrow + 2*SW, hrow + 3*SW);
            hv[0] = h3[0]; hv[2] = h3[1]; hv[3] = h3[2]; hv[1] = ownv; break;
          case 2:
            if (lane > 0) ld_h3p4(h3, pv, hrow + 0*SW, hrow + 1*SW, hrow + 3*SW, prow);
            else          ld_h3(h3, hrow + 0*SW, hrow + 1*SW, hrow + 3*SW);
            hv[0] = h3[0]; hv[1] = h3[1]; hv[3] = h3[2]; hv[2] = ownv; break;
          default:
            if (lane > 0) ld_h3p4(h3, pv, hrow + 0*SW, hrow + 1*SW, hrow + 2*SW, prow);
            else          ld_h3(h3, hrow + 0*SW, hrow + 1*SW, hrow + 2*SW);
            hv[0] = h3[0]; hv[1] = h3[1]; hv[2] = h3[2]; hv[3] = ownv; break;
        }
      } else {
        #pragma unroll
        for (int j = 0; j < 4; ++j) hv[j] = make_float4(0.f, 0.f, 0.f, 0.f);
        if (lane > 0) cload_row(pv, prow);
      }

      if (lane > 0) {
        float gs = 0.0f;
        #pragma unroll
        for (int j = 0; j < 4; ++j) {
          const float* wh = &wg_lds[j * 128 + gch * 4];
          const float* wp = wh + S;
          gs += hv[j].x * wh[0] + hv[j].y * wh[1] + hv[j].z * wh[2] + hv[j].w * wh[3];
          gs += pv[j].x * wp[0] + pv[j].y * wp[1] + pv[j].z * wp[2] + pv[j].w * wp[3];
        }
        gs += __shfl_xor(gs, 1);  gs += __shfl_xor(gs, 2);  gs += __shfl_xor(gs, 4);
        gs += __shfl_xor(gs, 8);  gs += __shfl_xor(gs, 16);  // 32-lane row halves
        const float w = 1.0f / (1.0f + __expf(-(gs + bg)));
        #pragma unroll
        for (int j = 0; j < 4; ++j) {  // hc = p + w*(h-p)
          hv[j].x = fmaf(w, hv[j].x - pv[j].x, pv[j].x);
          hv[j].y = fmaf(w, hv[j].y - pv[j].y, pv[j].y);
          hv[j].z = fmaf(w, hv[j].z - pv[j].z, pv[j].z);
          hv[j].w = fmaf(w, hv[j].w - pv[j].w, pv[j].w);
        }
      }
      #pragma unroll
      for (int j = 0; j < 4; ++j) {
        ushort4 h4, l4;
        h4.x = bf_hi(hv[j].x); l4.x = bf_hi(hv[j].x - bf_hi_f(hv[j].x));
        h4.y = bf_hi(hv[j].y); l4.y = bf_hi(hv[j].y - bf_hi_f(hv[j].y));
        h4.z = bf_hi(hv[j].z); l4.z = bf_hi(hv[j].z - bf_hi_f(hv[j].z));
        h4.w = bf_hi(hv[j].w); l4.w = bf_hi(hv[j].w - bf_hi_f(hv[j].w));
        const int ai = grow * AS + 32 + j * 128 + gch * 4;
        *(ushort4*)&A1[ai] = h4;
        *(ushort4*)&A2[ai] = l4;
      }
    }
    __syncthreads();

    // ---- phase C: MFMA, dual accumulator chains --------------------------
    f32x4 acc0 = {0.f, 0.f, 0.f, 0.f}, acc1 = {0.f, 0.f, 0.f, 0.f};
    {
      const unsigned short* ar1 = &A1[bn * AS + q * 8];
      const unsigned short* ar2 = &A2[bn * AS + q * 8];
      #pragma unroll
      for (int kt = 0; kt < NKT; ++kt) {
        const short8 a1 = *(const short8*)(ar1 + kt * 32);
        const short8 a2 = *(const short8*)(ar2 + kt * 32);
        if (kt < 9) {
          acc0 = __builtin_amdgcn_mfma_f32_16x16x32_bf16(a1, B1[kt], acc0, 0, 0, 0);
          acc0 = __builtin_amdgcn_mfma_f32_16x16x32_bf16(a1, B2[kt], acc0, 0, 0, 0);
          acc0 = __builtin_amdgcn_mfma_f32_16x16x32_bf16(a2, B1[kt], acc0, 0, 0, 0);
        } else {
          acc1 = __builtin_amdgcn_mfma_f32_16x16x32_bf16(a1, B1[kt], acc1, 0, 0, 0);
          acc1 = __builtin_amdgcn_mfma_f32_16x16x32_bf16(a1, B2[kt], acc1, 0, 0, 0);
          acc1 = __builtin_amdgcn_mfma_f32_16x16x32_bf16(a2, B1[kt], acc1, 0, 0, 0);
        }
      }
    }

    // ---- epilogue 1: bias+tanh -> h_lds (own block, f32) -----------------
    #pragma unroll
    for (int reg = 0; reg < 4; ++reg) {
      const float s2 = acc0[reg] + acc1[reg] + bcv;
      const float aa = fabsf(s2), ee = __expf(2.0f * aa);
      const float tv = copysignf(1.0f - 2.0f / (ee + 1.0f), s2);
      h_lds[(q * 4 + reg) * SW + wt * 16 + bn] = tv;
      if (t == T - 1) oacc[reg] = tv * wov;
    }
    __syncthreads();   // h_lds complete

    // ---- epilogue 2: COALESCED ring store (one dwordx4/thread) -----------
    {
      const f32x4 v = *(const f32x4*)&h_lds[grow * SW + gch * 4];
      float* dst = ring + ((size_t)(lane * DEPTH + (t & 3)) * BATCH + r0 + grow) * S + sb + gch * 4;
      cstore4f_glb(dst, v);
    }
    asm volatile("s_waitcnt vmcnt(0)" ::: "memory");  // own stores at MALL
    __syncthreads();  // all threads drained -> canary may publish
    if (tid < 16)
      cstoreu_glb(can + ((((lane * 4 + (t & 3)) * 16 + grp) * 16 + tid) * 4 + sl),
                  (unsigned)(t + 1));
    else if (tid == 16)
      cstoreu_glb(st_mine, (unsigned)(t + 1));
  }

  // ---- output: out[lane*256 + r] = h_T[r] . Wout --------------------------
  #pragma unroll
  for (int reg = 0; reg < 4; ++reg) {
    float v = oacc[reg];
    v += __shfl_xor(v, 1); v += __shfl_xor(v, 2);
    v += __shfl_xor(v, 4); v += __shfl_xor(v, 8);  // sum 16 cols of the tile
    if (bn == 0) obuf[wt * 16 + q * 4 + reg] = v;
  }
  __syncthreads();
  if (tid < 16) {
    float v = 0.0f;
    #pragma unroll
    for (int w = 0; w < 8; ++w) v += obuf[w * 16 + tid];
    cstore1(ws + OUTP_OFF + (size_t)((gid * 4 + sl) * 16 + tid), v);
  }
  asm volatile("s_waitcnt vmcnt(0)" ::: "memory");
  __syncthreads();
  if (tid == 0) cstoreu_glb(st_mine, (unsigned)(T + 1));
  if (sl == 0) {
    if (tid == 0)
      while (umin4(cld4_glb(st_own)) < (unsigned)(T + 1)) __builtin_amdgcn_s_sleep(1);
    __syncthreads();
    if (tid < 64) {
      const int sli = tid >> 4, r = tid & 15;
      fbuf[tid] = cload1(ws + OUTP_OFF + (size_t)((gid * 4 + sli) * 16 + r));
    }
    __syncthreads();
    if (tid < 16) {
      float s2 = 0.f;
      #pragma unroll
      for (int sli = 0; sli < 4; ++sli) s2 += fbuf[sli * 16 + tid];
      out[lane * BATCH + r0 + tid] = s2;
    }
  }
}

extern "C" void kernel_launch(void* const* d_in, const int* in_sizes, int n_in,
                              void* d_out, int out_size, void* d_ws, size_t ws_size,
                              hipStream_t stream) {
  (void)in_sizes; (void)n_in; (void)out_size; (void)ws_size;
  rnn_mfma<<<dim3(NWG), dim3(NT), 0, stream>>>(
      (const float*)d_in[0],   // inputs
      (const float*)d_in[1],   // W_cell
      (const float*)d_in[2],   // b_cell
      (const float*)d_in[3],   // W_comb
      (const float*)d_in[4],   // b_comb
      (const float*)d_in[5],   // W_out
      (float*)d_out,
      (float*)d_ws);
}